// Round 1
// baseline (723.916 us; speedup 1.0000x reference)
//
#include <hip/hip_runtime.h>

#define F_DIM 128
#define C_DIM 100000
#define B_ROWS 512
#define ANGLE 0.5f

typedef __attribute__((ext_vector_type(4))) float  f32x4;
typedef __attribute__((ext_vector_type(8))) short  bf16x8;
typedef __attribute__((ext_vector_type(4))) short  bf16x4;

static __device__ __forceinline__ unsigned short f2bf(float x) {
    unsigned int u = __float_as_uint(x);
    u += 0x7FFFu + ((u >> 16) & 1u);      // RNE
    return (unsigned short)(u >> 16);
}

// ---------------------------------------------------------------------------
// Kernel 2: exact fp32 target-column terms. One wave per row b.
//   margin[b] = mod * cos(acos(dot/(mod*1.01)) + ANGLE),  mod = |f_b||w_:t|
//   logit_t[b] = dot(f_b, w[:, t_b])
// ---------------------------------------------------------------------------
__global__ void arc_target(const float* __restrict__ feat,
                           const float* __restrict__ w,
                           const int*   __restrict__ target,
                           float* __restrict__ marg,
                           float* __restrict__ logit_t)
{
    const int b    = blockIdx.x;
    const int lane = threadIdx.x;             // 64
    const int t    = target[b];

    float dot = 0.f, wsq = 0.f, fsq = 0.f;
    #pragma unroll
    for (int h = 0; h < 2; ++h) {
        const int f  = lane + h * 64;
        const float fv = feat[b * F_DIM + f];
        const float wv = w[(size_t)f * C_DIM + t];
        dot += fv * wv;
        wsq += wv * wv;
        fsq += fv * fv;
    }
    #pragma unroll
    for (int off = 32; off > 0; off >>= 1) {
        dot += __shfl_xor(dot, off);
        wsq += __shfl_xor(wsq, off);
        fsq += __shfl_xor(fsq, off);
    }
    if (lane == 0) {
        const float mod = sqrtf(fsq) * sqrtf(wsq);
        float ct = dot / (mod * 1.01f);
        ct = fminf(1.f, fmaxf(-1.f, ct));
        const float th = acosf(ct) + ANGLE;
        marg[b]    = mod * cosf(th);
        logit_t[b] = dot;
    }
}

// ---------------------------------------------------------------------------
// Kernel 3: main fused GEMM + exp + row-sum.
//   grid (ceil(C/128), 4): each block = 128 rows x 128 cols, K=128.
//   LDS: lA 128x128 bf16 (16B-chunk XOR swizzle, conflict-free ds_read_b128
//        A-frags), lB 128x128 bf16 natural [k][c] (u16 frag reads).
//   Exactly 64 KB LDS -> 2 blocks/CU for stage/compute overlap.
// ---------------------------------------------------------------------------
__global__ __launch_bounds__(256, 2)
void arc_main(const float* __restrict__ feat,
              const float* __restrict__ w,
              float* __restrict__ sumexp)
{
    __shared__ unsigned short lA[128 * 128];  // [row][k], swizzled 16B chunks
    __shared__ unsigned short lB[128 * 128];  // [k][c], natural

    const int tid = threadIdx.x;
    const int c0  = blockIdx.x * 128;         // column tile base
    const int r0  = blockIdx.y * 128;         // row group base

    // ---- stage A: features fp32 -> bf16, swizzled ----
    #pragma unroll
    for (int it = 0; it < 16; ++it) {
        const int idx4 = it * 256 + tid;      // float4 index 0..4095
        const int row  = idx4 >> 5;           // 0..127
        const int c4   = idx4 & 31;           // float4 within the 128-wide row
        const f32x4 v  = *(const f32x4*)(feat + (size_t)(r0 + row) * F_DIM + c4 * 4);
        bf16x4 h;
        h[0] = (short)f2bf(v[0]); h[1] = (short)f2bf(v[1]);
        h[2] = (short)f2bf(v[2]); h[3] = (short)f2bf(v[3]);
        const int pc   = (c4 >> 1) ^ (row & 15);   // 16B-chunk XOR swizzle
        const int half = c4 & 1;
        *(bf16x4*)&lA[row * 128 + pc * 8 + half * 4] = h;
    }

    // ---- stage B: w fp32 -> bf16, natural [k][c], OOB cols -> 0 ----
    #pragma unroll
    for (int it = 0; it < 16; ++it) {
        const int idx4 = it * 256 + tid;
        const int k    = idx4 >> 5;           // 0..127
        const int c4   = idx4 & 31;
        const int c    = c0 + c4 * 4;
        f32x4 v = {0.f, 0.f, 0.f, 0.f};
        if (c < C_DIM)                        // C and c are multiples of 4
            v = *(const f32x4*)(w + (size_t)k * C_DIM + c);
        bf16x4 h;
        h[0] = (short)f2bf(v[0]); h[1] = (short)f2bf(v[1]);
        h[2] = (short)f2bf(v[2]); h[3] = (short)f2bf(v[3]);
        *(bf16x4*)&lB[k * 128 + c4 * 4] = h;
    }
    __syncthreads();

    const int lane = tid & 63;
    const int wv   = tid >> 6;                // wave 0..3
    const int quad = lane >> 4;
    const int l15  = lane & 15;
    const int nb   = wv * 32;                 // wave's 32-col strip

    f32x4 acc[8][2];
    #pragma unroll
    for (int m = 0; m < 8; ++m) {
        acc[m][0] = (f32x4){0.f, 0.f, 0.f, 0.f};
        acc[m][1] = (f32x4){0.f, 0.f, 0.f, 0.f};
    }

    #pragma unroll
    for (int ks = 0; ks < 4; ++ks) {
        // B-frags: B[k = ks*32 + quad*8 + j][n = nb + s*16 + l15]
        bf16x8 bfr[2];
        #pragma unroll
        for (int s = 0; s < 2; ++s) {
            #pragma unroll
            for (int j = 0; j < 8; ++j)
                bfr[s][j] = (short)lB[(ks * 32 + quad * 8 + j) * 128 + nb + s * 16 + l15];
        }
        // A-frags: A[m-row = m*16 + l15][k = ks*32 + quad*8 + j], b128 swizzled
        #pragma unroll
        for (int m = 0; m < 8; ++m) {
            const int row = m * 16 + l15;
            const int pc  = (ks * 4 + quad) ^ (row & 15);
            const bf16x8 af = *(const bf16x8*)&lA[row * 128 + pc * 8];
            acc[m][0] = __builtin_amdgcn_mfma_f32_16x16x32_bf16(af, bfr[0], acc[m][0], 0, 0, 0);
            acc[m][1] = __builtin_amdgcn_mfma_f32_16x16x32_bf16(af, bfr[1], acc[m][1], 0, 0, 0);
        }
    }

    // ---- epilogue: exp, reduce 16 cols per quad, atomicAdd per row ----
    const int  col0 = c0 + nb + l15;
    const int  col1 = col0 + 16;
    const bool v0   = col0 < C_DIM;
    const bool v1   = col1 < C_DIM;
    #pragma unroll
    for (int m = 0; m < 8; ++m) {
        #pragma unroll
        for (int r = 0; r < 4; ++r) {
            float s = 0.f;
            if (v0) s += __expf(acc[m][0][r]);
            if (v1) s += __expf(acc[m][1][r]);
            #pragma unroll
            for (int off = 1; off < 16; off <<= 1)
                s += __shfl_xor(s, off);      // sum 16 cols within quad group
            if (l15 == 0)                     // D row = m*16 + quad*4 + r
                atomicAdd(sumexp + r0 + m * 16 + quad * 4 + r, s);
        }
    }
}

// ---------------------------------------------------------------------------
// Kernel 4: final loss = -(1/B) sum_b [ margin_b - log(down_b) ]
//   down_b = sumexp_b - exp(logit_t_b) + exp(margin_b)
// ---------------------------------------------------------------------------
__global__ void arc_final(const float* __restrict__ sumexp,
                          const float* __restrict__ marg,
                          const float* __restrict__ logit_t,
                          float* __restrict__ out)
{
    __shared__ float red[B_ROWS];
    const int b = threadIdx.x;
    const float m    = marg[b];
    const float top  = expf(m);
    const float down = sumexp[b] - expf(logit_t[b]) + top;
    red[b] = m - logf(down);
    __syncthreads();
    #pragma unroll
    for (int st = 256; st > 0; st >>= 1) {
        if (b < st) red[b] += red[b + st];
        __syncthreads();
    }
    if (b == 0) out[0] = -red[0] / (float)B_ROWS;
}

// ---------------------------------------------------------------------------
extern "C" void kernel_launch(void* const* d_in, const int* in_sizes, int n_in,
                              void* d_out, int out_size, void* d_ws, size_t ws_size,
                              hipStream_t stream)
{
    const float* feat   = (const float*)d_in[0];   // [512,128] fp32
    const float* w      = (const float*)d_in[1];   // [128,100000] fp32
    const int*   target = (const int*)d_in[2];     // [512]

    float* sumexp  = (float*)d_ws;                 // [512]
    float* marg    = sumexp + 512;                 // [512]
    float* logit_t = sumexp + 1024;                // [512]

    hipMemsetAsync(sumexp, 0, 512 * sizeof(float), stream);
    arc_target<<<512, 64, 0, stream>>>(feat, w, target, marg, logit_t);
    arc_main<<<dim3((C_DIM + 127) / 128, 4), 256, 0, stream>>>(feat, w, sumexp);
    arc_final<<<1, B_ROWS, 0, stream>>>(sumexp, marg, logit_t, (float*)d_out);
}

// Round 2
// 144.025 us; speedup vs baseline: 5.0263x; 5.0263x over previous
//
#include <hip/hip_runtime.h>

#define F_DIM 128
#define C_DIM 100000
#define B_ROWS 512
#define ANGLE 0.5f
#define NXB 196            // ceil(100000 / 512) column-blocks
#define COLS_PER_BLK 512   // 4 subtiles of 128

typedef __attribute__((ext_vector_type(4))) float  f32x4;
typedef __attribute__((ext_vector_type(8))) short  bf16x8;
typedef __attribute__((ext_vector_type(4))) short  bf16x4;

static __device__ __forceinline__ unsigned short f2bf(float x) {
    unsigned int u = __float_as_uint(x);
    u += 0x7FFFu + ((u >> 16) & 1u);      // RNE
    return (unsigned short)(u >> 16);
}

// ---------------------------------------------------------------------------
// Main fused GEMM + exp + row partial sums. NO global atomics.
//   grid (4, 196): x = row group (128 rows), y = 512-col block.
//   Per block: stage A once (swizzled bf16), loop 4 column-subtiles of 128:
//   stage B, MFMA (16x16x32 bf16), accumulate exp into per-lane registers.
//   End: 16-lane shuffle reduce -> LDS atomic (cheap, shared scope) ->
//   one non-atomic global write per row: pp[row][blockIdx.y].
// ---------------------------------------------------------------------------
__global__ __launch_bounds__(256, 2)
void arc_main(const float* __restrict__ feat,
              const float* __restrict__ w,
              float* __restrict__ pp)
{
    __shared__ unsigned short lA[128 * 128];  // [row][k], XOR-swizzled 16B chunks
    __shared__ unsigned short lB[128 * 128];  // [k][c], natural
    __shared__ float lRow[128];

    const int tid    = threadIdx.x;
    const int r0     = blockIdx.x * 128;
    const int cblk   = blockIdx.y;
    const int cbase0 = cblk * COLS_PER_BLK;

    if (tid < 128) lRow[tid] = 0.f;

    // ---- stage A (features) fp32 -> bf16, swizzled; once per block ----
    #pragma unroll
    for (int it = 0; it < 16; ++it) {
        const int idx4 = it * 256 + tid;      // float4 index 0..4095
        const int row  = idx4 >> 5;           // 0..127
        const int c4   = idx4 & 31;
        const f32x4 v  = *(const f32x4*)(feat + (size_t)(r0 + row) * F_DIM + c4 * 4);
        bf16x4 h;
        h[0] = (short)f2bf(v[0]); h[1] = (short)f2bf(v[1]);
        h[2] = (short)f2bf(v[2]); h[3] = (short)f2bf(v[3]);
        const int pc   = (c4 >> 1) ^ (row & 15);
        const int half = c4 & 1;
        *(bf16x4*)&lA[row * 128 + pc * 8 + half * 4] = h;
    }

    const int lane = tid & 63;
    const int wv   = tid >> 6;
    const int quad = lane >> 4;
    const int l15  = lane & 15;
    const int nb   = wv * 32;

    float esum[8][4];
    #pragma unroll
    for (int m = 0; m < 8; ++m)
        #pragma unroll
        for (int r = 0; r < 4; ++r) esum[m][r] = 0.f;

    for (int t = 0; t < 4; ++t) {
        const int cbase = cbase0 + t * 128;

        // ---- stage B (w subtile) fp32 -> bf16, natural [k][c], OOB -> 0 ----
        #pragma unroll
        for (int it = 0; it < 16; ++it) {
            const int idx4 = it * 256 + tid;
            const int k    = idx4 >> 5;
            const int c4   = idx4 & 31;
            const int c    = cbase + c4 * 4;
            f32x4 v = {0.f, 0.f, 0.f, 0.f};
            if (c < C_DIM)
                v = *(const f32x4*)(w + (size_t)k * C_DIM + c);
            bf16x4 h;
            h[0] = (short)f2bf(v[0]); h[1] = (short)f2bf(v[1]);
            h[2] = (short)f2bf(v[2]); h[3] = (short)f2bf(v[3]);
            *(bf16x4*)&lB[k * 128 + c4 * 4] = h;
        }
        __syncthreads();

        f32x4 acc[8][2];
        #pragma unroll
        for (int m = 0; m < 8; ++m) {
            acc[m][0] = (f32x4){0.f, 0.f, 0.f, 0.f};
            acc[m][1] = (f32x4){0.f, 0.f, 0.f, 0.f};
        }

        #pragma unroll
        for (int ks = 0; ks < 4; ++ks) {
            bf16x8 bfr[2];
            #pragma unroll
            for (int s = 0; s < 2; ++s) {
                #pragma unroll
                for (int j = 0; j < 8; ++j)
                    bfr[s][j] = (short)lB[(ks * 32 + quad * 8 + j) * 128 + nb + s * 16 + l15];
            }
            #pragma unroll
            for (int m = 0; m < 8; ++m) {
                const int row = m * 16 + l15;
                const int pc  = (ks * 4 + quad) ^ (row & 15);
                const bf16x8 af = *(const bf16x8*)&lA[row * 128 + pc * 8];
                acc[m][0] = __builtin_amdgcn_mfma_f32_16x16x32_bf16(af, bfr[0], acc[m][0], 0, 0, 0);
                acc[m][1] = __builtin_amdgcn_mfma_f32_16x16x32_bf16(af, bfr[1], acc[m][1], 0, 0, 0);
            }
        }

        // ---- exp accumulate (per-lane registers, guard OOB cols) ----
        const int  col0 = cbase + nb + l15;
        const int  col1 = col0 + 16;
        const bool v0   = col0 < C_DIM;
        const bool v1   = col1 < C_DIM;
        #pragma unroll
        for (int m = 0; m < 8; ++m) {
            #pragma unroll
            for (int r = 0; r < 4; ++r) {
                if (v0) esum[m][r] += __expf(acc[m][0][r]);
                if (v1) esum[m][r] += __expf(acc[m][1][r]);
            }
        }
        __syncthreads();   // lB consumed; safe to restage next subtile
    }

    // ---- reduce: 16 lanes (cols) -> 1, then cross-wave via LDS atomics ----
    #pragma unroll
    for (int m = 0; m < 8; ++m) {
        #pragma unroll
        for (int r = 0; r < 4; ++r) {
            float s = esum[m][r];
            #pragma unroll
            for (int off = 1; off < 16; off <<= 1)
                s += __shfl_xor(s, off);
            if (l15 == 0)
                atomicAdd(&lRow[m * 16 + quad * 4 + r], s);  // shared-scope: fast
        }
    }
    __syncthreads();
    if (tid < 128)
        pp[(size_t)(r0 + tid) * NXB + cblk] = lRow[tid];
}

// ---------------------------------------------------------------------------
// Per-row: exact fp32 target-column terms + partial-sum reduce.
//   One wave per row b. term[b] = margin - log(down).
// ---------------------------------------------------------------------------
__global__ void arc_row(const float* __restrict__ feat,
                        const float* __restrict__ w,
                        const int*   __restrict__ target,
                        const float* __restrict__ pp,
                        float* __restrict__ term)
{
    const int b    = blockIdx.x;
    const int lane = threadIdx.x;             // 64
    const int t    = target[b];

    float dot = 0.f, wsq = 0.f, fsq = 0.f, rs = 0.f;
    #pragma unroll
    for (int h = 0; h < 2; ++h) {
        const int f  = lane + h * 64;
        const float fv = feat[b * F_DIM + f];
        const float wv = w[(size_t)f * C_DIM + t];
        dot += fv * wv;
        wsq += wv * wv;
        fsq += fv * fv;
    }
    for (int j = lane; j < NXB; j += 64)
        rs += pp[(size_t)b * NXB + j];

    #pragma unroll
    for (int off = 32; off > 0; off >>= 1) {
        dot += __shfl_xor(dot, off);
        wsq += __shfl_xor(wsq, off);
        fsq += __shfl_xor(fsq, off);
        rs  += __shfl_xor(rs,  off);
    }
    if (lane == 0) {
        const float mod = sqrtf(fsq) * sqrtf(wsq);
        float ct = dot / (mod * 1.01f);
        ct = fminf(1.f, fmaxf(-1.f, ct));
        const float th   = acosf(ct) + ANGLE;
        const float marg = mod * cosf(th);
        const float down = rs - expf(dot) + expf(marg);
        term[b] = marg - logf(down);
    }
}

// ---------------------------------------------------------------------------
// Final: loss = -(1/B) sum_b term[b]
// ---------------------------------------------------------------------------
__global__ void arc_loss(const float* __restrict__ term,
                         float* __restrict__ out)
{
    __shared__ float red[B_ROWS];
    const int b = threadIdx.x;
    red[b] = term[b];
    __syncthreads();
    #pragma unroll
    for (int st = 256; st > 0; st >>= 1) {
        if (b < st) red[b] += red[b + st];
        __syncthreads();
    }
    if (b == 0) out[0] = -red[0] / (float)B_ROWS;
}

// ---------------------------------------------------------------------------
extern "C" void kernel_launch(void* const* d_in, const int* in_sizes, int n_in,
                              void* d_out, int out_size, void* d_ws, size_t ws_size,
                              hipStream_t stream)
{
    const float* feat   = (const float*)d_in[0];   // [512,128] fp32
    const float* w      = (const float*)d_in[1];   // [128,100000] fp32
    const int*   target = (const int*)d_in[2];     // [512]

    float* pp   = (float*)d_ws;                    // [512][196] partials
    float* term = pp + (size_t)B_ROWS * NXB;       // [512]

    arc_main<<<dim3(4, NXB), 256, 0, stream>>>(feat, w, pp);
    arc_row<<<B_ROWS, 64, 0, stream>>>(feat, w, target, pp, term);
    arc_loss<<<1, B_ROWS, 0, stream>>>(term, (float*)d_out);
}